// Round 1
// baseline (461.730 us; speedup 1.0000x reference)
//
#include <hip/hip_runtime.h>

#define NB 8
#define NT 30000
#define NL 6
#define NH 128
#define NW 128
#define NC 32
#define NHID 256

typedef _Float16 f16;
typedef _Float16 half8 __attribute__((ext_vector_type(8)));

// Precompute folded shortcut: M = blk0_ws @ fc_p_w (32x3), v = blk0_ws @ fc_p_b (32)
// Stored as float4 {M0,M1,M2,v} per output channel in d_ws.
__global__ void fold_kernel(const float* __restrict__ ws, const float* __restrict__ fpw,
                            const float* __restrict__ fpb, float4* __restrict__ out) {
    int i = threadIdx.x;
    if (i < NC) {
        float m0 = 0.f, m1 = 0.f, m2 = 0.f, v = 0.f;
        for (int k = 0; k < NHID; k++) {
            float w = ws[i * NHID + k];
            m0 = fmaf(w, fpw[k * 3 + 0], m0);
            m1 = fmaf(w, fpw[k * 3 + 1], m1);
            m2 = fmaf(w, fpw[k * 3 + 2], m2);
            v  = fmaf(w, fpb[k], v);
        }
        out[i] = make_float4(m0, m1, m2, v);
    }
}

__launch_bounds__(256, 4)
__global__ void decoder_kernel(
    const float* __restrict__ p, const float* __restrict__ c, const float* __restrict__ Cm,
    const float* __restrict__ fpw, const float* __restrict__ fpb,
    const float* __restrict__ b0w0, const float* __restrict__ b0b0,
    const float* __restrict__ b0w1, const float* __restrict__ b0b1,
    const float* __restrict__ bw0, const float* __restrict__ bb0,
    const float* __restrict__ bw1, const float* __restrict__ bb1,
    const float* __restrict__ fow, const float* __restrict__ fob,
    const float4* __restrict__ fold, float* __restrict__ out)
{
    // Weights in LDS. Matmul weights as f16 (they are ~N(0,0.1); rel err 5e-4).
    // Transposed layouts: [k][i] so the 32 outputs per k are contiguous (b128 reads).
    __shared__ half8 s_w0T[NHID][4];   // 16 KB  w0T[j][i] = blk0_w0[i][j]
    __shared__ half8 s_w10T[NC][4];    // 2 KB   blk0_w1[i][k] -> [k][i]
    __shared__ half8 s_bw0T[4][NC][4]; // 8 KB
    __shared__ half8 s_bw1T[4][NC][4]; // 8 KB
    __shared__ float4 s_fcp[NHID];     // 4 KB   {w0,w1,w2,b} per hidden unit (fp32, relu cuts)
    __shared__ float4 s_fold[NC];      // folded shortcut rows
    __shared__ float s_b00[NC], s_b10[NC];
    __shared__ float s_bb0[4][NC], s_bb1[4][NC];
    __shared__ float s_fow[NC];
    __shared__ float s_fob;
    __shared__ float s_cam[NL][6];     // folded projection coeffs per view

    const int tid = threadIdx.x;
    const int b = blockIdx.y;
    const float inv_int = 1.0f / (2.0f / 127.0f);  // 1/interval

    // ---- preload weights into LDS ----
    {
        f16* w0p = (f16*)s_w0T;
        for (int idx = tid; idx < NHID * NC; idx += 256) {
            int j = idx >> 5, i = idx & 31;
            w0p[idx] = (f16)b0w0[i * NHID + j];
        }
        f16* w1p = (f16*)s_w10T;
        for (int idx = tid; idx < NC * NC; idx += 256) {
            int k = idx >> 5, i = idx & 31;
            w1p[idx] = (f16)b0w1[i * NC + k];
        }
        f16* bw0p = (f16*)s_bw0T;
        f16* bw1p = (f16*)s_bw1T;
        for (int idx = tid; idx < 4 * NC * NC; idx += 256) {
            int blk = idx >> 10, r = idx & 1023;
            int k = r >> 5, i = r & 31;
            bw0p[idx] = (f16)bw0[(blk * NC + i) * NC + k];
            bw1p[idx] = (f16)bw1[(blk * NC + i) * NC + k];
        }
        s_fcp[tid] = make_float4(fpw[tid * 3 + 0], fpw[tid * 3 + 1], fpw[tid * 3 + 2], fpb[tid]);
        if (tid < NC) {
            s_b00[tid] = b0b0[tid];
            s_b10[tid] = b0b1[tid];
            s_fow[tid] = fow[tid];
            s_fold[tid] = fold[tid];
        }
        if (tid >= NC && tid < NC + 4 * NC) {
            int q = tid - NC;
            int blk = q >> 5, i = q & 31;
            s_bb0[blk][i] = bb0[q];
            s_bb1[blk][i] = bb1[q];
        }
        if (tid == 0) s_fob = fob[0];
        if (tid >= 192 && tid < 192 + NL) {
            int l = tid - 192;
            const float* cm = Cm + ((size_t)b * NL + l) * 12;
            float denom = cm[9] + 0.05f;          // row 3, col 0 (== 1.0) + 0.05
            float s = inv_int / (0.55f * denom);  // fold /MAX_DIM, /denom, *inv_interval
            s_cam[l][0] = cm[0] * s; s_cam[l][1] = cm[1] * s; s_cam[l][2] = cm[2] * s;
            s_cam[l][3] = cm[3] * s; s_cam[l][4] = cm[4] * s; s_cam[l][5] = cm[5] * s;
        }
    }
    __syncthreads();

    const int t = blockIdx.x * 256 + tid;
    if (t >= NT) return;

    const float* pp = p + ((size_t)b * NT + t) * 3;
    float px = pp[0], py = pp[1], pz = pp[2];

    // ---- bilinear multi-view feature gather ----
    float feat[NC];
    #pragma unroll
    for (int i = 0; i < NC; i++) feat[i] = 0.f;

    #pragma unroll 1
    for (int l = 0; l < NL; l++) {
        float x = s_cam[l][0] * px + s_cam[l][1] * py + s_cam[l][2] * pz + inv_int;
        float y = s_cam[l][3] * px + s_cam[l][4] * py + s_cam[l][5] * pz + inv_int;
        float x0f = floorf(x), x1f = ceilf(x);
        float y0f = floorf(y), y1f = ceilf(y);
        float dxw = x1f - x, dyw = y1f - y;
        int x0 = min(max((int)x0f, 0), NH - 1);
        int x1 = min(max((int)x1f, 0), NH - 1);
        int y0 = min(max((int)y0f, 0), NW - 1);
        int y1 = min(max((int)y1f, 0), NW - 1);
        const float* base = c + (((size_t)(b * NL + l)) << 19);  // * 128*128*32
        const float4* f11 = (const float4*)(base + (size_t)((x0 << 7) + y0) * NC);
        const float4* f12 = (const float4*)(base + (size_t)((x1 << 7) + y0) * NC);
        const float4* f21 = (const float4*)(base + (size_t)((x0 << 7) + y1) * NC);
        const float4* f22 = (const float4*)(base + (size_t)((x1 << 7) + y1) * NC);
        float w11 = dxw * dyw;
        float w12 = (1.f - dxw) * dyw;
        float w21 = dxw * (1.f - dyw);
        float w22 = (1.f - dxw) * (1.f - dyw);
        #pragma unroll
        for (int g = 0; g < 8; g++) {
            float4 a = f11[g], bb_ = f12[g], cc_ = f21[g], dd_ = f22[g];
            feat[g * 4 + 0] += a.x * w11 + bb_.x * w12 + cc_.x * w21 + dd_.x * w22;
            feat[g * 4 + 1] += a.y * w11 + bb_.y * w12 + cc_.y * w21 + dd_.y * w22;
            feat[g * 4 + 2] += a.z * w11 + bb_.z * w12 + cc_.z * w21 + dd_.z * w22;
            feat[g * 4 + 3] += a.w * w11 + bb_.w * w12 + cc_.w * w21 + dd_.w * w22;
        }
    }

    // ---- blk0: h0 = b00 + W0 @ relu(A p + b)  (256 hidden, fused) ----
    float acc[NC];
    #pragma unroll
    for (int i = 0; i < NC; i++) acc[i] = s_b00[i];
    #pragma unroll 2
    for (int j = 0; j < NHID; j++) {
        float4 fw = s_fcp[j];
        float r = fmaxf(fw.x * px + fw.y * py + fw.z * pz + fw.w, 0.f);
        #pragma unroll
        for (int i8 = 0; i8 < 4; i8++) {
            half8 h8 = s_w0T[j][i8];
            #pragma unroll
            for (int u = 0; u < 8; u++)
                acc[i8 * 8 + u] = fmaf((float)h8[u], r, acc[i8 * 8 + u]);
        }
    }

    // ---- net32 = folded_shortcut(p) + b10 + W1 @ relu(h0) + feat ----
    float net32[NC];
    #pragma unroll
    for (int i = 0; i < NC; i++) {
        float4 f = s_fold[i];
        net32[i] = f.x * px + f.y * py + f.z * pz + f.w + s_b10[i] + feat[i];
    }
    #pragma unroll 4
    for (int k = 0; k < NC; k++) {
        float r = fmaxf(acc[k], 0.f);
        #pragma unroll
        for (int i8 = 0; i8 < 4; i8++) {
            half8 h8 = s_w10T[k][i8];
            #pragma unroll
            for (int u = 0; u < 8; u++)
                net32[i8 * 8 + u] = fmaf((float)h8[u], r, net32[i8 * 8 + u]);
        }
    }

    // ---- residual blocks 1..4 ----
    #pragma unroll 1
    for (int blk = 0; blk < 4; blk++) {
        float h[NC];
        #pragma unroll
        for (int i = 0; i < NC; i++) h[i] = s_bb0[blk][i];
        #pragma unroll 4
        for (int k = 0; k < NC; k++) {
            float r = fmaxf(net32[k], 0.f);
            #pragma unroll
            for (int i8 = 0; i8 < 4; i8++) {
                half8 h8 = s_bw0T[blk][k][i8];
                #pragma unroll
                for (int u = 0; u < 8; u++)
                    h[i8 * 8 + u] = fmaf((float)h8[u], r, h[i8 * 8 + u]);
            }
        }
        #pragma unroll
        for (int i = 0; i < NC; i++) net32[i] += s_bb1[blk][i] + feat[i];
        #pragma unroll 4
        for (int k = 0; k < NC; k++) {
            float r = fmaxf(h[k], 0.f);
            #pragma unroll
            for (int i8 = 0; i8 < 4; i8++) {
                half8 h8 = s_bw1T[blk][k][i8];
                #pragma unroll
                for (int u = 0; u < 8; u++)
                    net32[i8 * 8 + u] = fmaf((float)h8[u], r, net32[i8 * 8 + u]);
            }
        }
    }

    // ---- output head ----
    float o = s_fob;
    #pragma unroll
    for (int i = 0; i < NC; i++) o = fmaf(fmaxf(net32[i], 0.f), s_fow[i], o);
    out[(size_t)b * NT + t] = o;
}

extern "C" void kernel_launch(void* const* d_in, const int* in_sizes, int n_in,
                              void* d_out, int out_size, void* d_ws, size_t ws_size,
                              hipStream_t stream) {
    const float* p    = (const float*)d_in[0];
    // d_in[1] = z : unused by the reference
    const float* c    = (const float*)d_in[2];
    const float* Cm   = (const float*)d_in[3];
    const float* fpw  = (const float*)d_in[4];
    const float* fpb  = (const float*)d_in[5];
    const float* b0w0 = (const float*)d_in[6];
    const float* b0b0 = (const float*)d_in[7];
    const float* b0w1 = (const float*)d_in[8];
    const float* b0b1 = (const float*)d_in[9];
    const float* b0ws = (const float*)d_in[10];
    const float* bw0  = (const float*)d_in[11];
    const float* bb0  = (const float*)d_in[12];
    const float* bw1  = (const float*)d_in[13];
    const float* bb1  = (const float*)d_in[14];
    const float* fow  = (const float*)d_in[15];
    const float* fob  = (const float*)d_in[16];
    float4* fold = (float4*)d_ws;

    fold_kernel<<<1, 64, 0, stream>>>(b0ws, fpw, fpb, fold);

    dim3 grid((NT + 255) / 256, NB);
    decoder_kernel<<<grid, 256, 0, stream>>>(p, c, Cm, fpw, fpb,
                                             b0w0, b0b0, b0w1, b0b1,
                                             bw0, bb0, bw1, bb1,
                                             fow, fob, fold, (float*)d_out);
}

// Round 2
// 307.386 us; speedup vs baseline: 1.5021x; 1.5021x over previous
//
#include <hip/hip_runtime.h>

#define NB 8
#define NT 30000
#define NL 6
#define NC 32
#define NHID 256

typedef _Float16 f16;
typedef f16 half8 __attribute__((ext_vector_type(8)));
typedef float floatx4 __attribute__((ext_vector_type(4)));

// Row permutation so MFMA D-layout lands in "lane(q) owns channels 8q..8q+7" order:
// D row m = m16*16 + 4q + r must hold true channel 8q + 4*m16 + r.
__device__ __forceinline__ int permrow(int m) {
    return 8 * ((m & 15) >> 2) + 4 * (m >> 4) + (m & 3);
}

// Precompute folded shortcut: M = blk0_ws @ fc_p_w (32x3), v = blk0_ws @ fc_p_b (32)
__global__ void fold_kernel(const float* __restrict__ ws, const float* __restrict__ fpw,
                            const float* __restrict__ fpb, floatx4* __restrict__ out) {
    int i = threadIdx.x;
    if (i < NC) {
        float m0 = 0.f, m1 = 0.f, m2 = 0.f, v = 0.f;
        for (int k = 0; k < NHID; k++) {
            float w = ws[i * NHID + k];
            m0 = fmaf(w, fpw[k * 3 + 0], m0);
            m1 = fmaf(w, fpw[k * 3 + 1], m1);
            m2 = fmaf(w, fpw[k * 3 + 2], m2);
            v  = fmaf(w, fpb[k], v);
        }
        out[i] = floatx4{m0, m1, m2, v};
    }
}

// One 32x32 (out x in) f16 GEMM step on 16 points: in[8] = relu-input state
// (true ch 8q+j), weights pre-permuted rows, rows padded to 40 f16.
__device__ __forceinline__ void gemm32(const f16* __restrict__ wmat, int i16, int q,
                                       const float in[8], floatx4& o0, floatx4& o1) {
    half8 bf;
    #pragma unroll
    for (int j = 0; j < 8; j++) bf[j] = (f16)fmaxf(in[j], 0.f);
    half8 a0 = *(const half8*)(wmat + i16 * 40 + q * 8);
    half8 a1 = *(const half8*)(wmat + (16 + i16) * 40 + q * 8);
    o0 = __builtin_amdgcn_mfma_f32_16x16x32_f16(a0, bf, o0, 0, 0, 0);
    o1 = __builtin_amdgcn_mfma_f32_16x16x32_f16(a1, bf, o1, 0, 0, 0);
}

__launch_bounds__(256, 3)
__global__ void decoder_kernel(
    const float* __restrict__ p, const float* __restrict__ c, const float* __restrict__ Cm,
    const float* __restrict__ fpw, const float* __restrict__ fpb,
    const float* __restrict__ b0w0, const float* __restrict__ b0b0,
    const float* __restrict__ b0w1, const float* __restrict__ b0b1,
    const float* __restrict__ bw0, const float* __restrict__ bb0,
    const float* __restrict__ bw1, const float* __restrict__ bb1,
    const float* __restrict__ fow, const float* __restrict__ fob,
    const floatx4* __restrict__ fold, float* __restrict__ out)
{
    // blk0_w0 A-rows: 32 rows x 256 k, rows padded to 288 f16 (576 B)
    __shared__ __align__(16) f16 s_w0A[32 * 288];            // 18.4 KB
    // 9 small mats (blk0_w1, then blk_w0[b], blk_w1[b] interleaved), rows padded to 40 f16
    __shared__ __align__(16) f16 s_wA[9 * 32 * 40];          // 23.0 KB
    __shared__ floatx4 s_fcp[288];                           // 4.6 KB  {w0,w1,w2,b}, gap every 8
    __shared__ floatx4 s_fold[36];                           // gap every 8
    __shared__ __align__(16) float s_b0b0[32], s_b0b1[32], s_fow[32];
    __shared__ __align__(16) float s_bb0f[128], s_bb1f[128];
    __shared__ float s_cam[NL][8];
    __shared__ float s_fob;

    const int tid = threadIdx.x;
    const int b = blockIdx.y;

    // ---- staging ----
    for (int idx = tid; idx < 32 * 256; idx += 256) {
        int m = idx >> 8, k = idx & 255;
        s_w0A[m * 288 + k] = (f16)b0w0[permrow(m) * 256 + k];
    }
    for (int idx = tid; idx < 9 * 1024; idx += 256) {
        int mi = idx >> 10, rem = idx & 1023;
        int m = rem >> 5, k = rem & 31;
        int pm = permrow(m);
        float v;
        if (mi == 0) v = b0w1[pm * 32 + k];
        else {
            int mat = mi - 1, bi = mat >> 1;
            v = (mat & 1) ? bw1[(bi * 32 + pm) * 32 + k] : bw0[(bi * 32 + pm) * 32 + k];
        }
        s_wA[mi * 1280 + m * 40 + k] = (f16)v;
    }
    {
        int k = tid;
        s_fcp[k + (k >> 3)] = floatx4{fpw[k * 3 + 0], fpw[k * 3 + 1], fpw[k * 3 + 2], fpb[k]};
    }
    if (tid < 32) {
        s_b0b0[tid] = b0b0[tid];
        s_b0b1[tid] = b0b1[tid];
        s_fow[tid]  = fow[tid];
        s_fold[tid + (tid >> 3)] = fold[tid];
    }
    if (tid >= 64 && tid < 192) {
        int j = tid - 64;
        s_bb0f[j] = bb0[j];
        s_bb1f[j] = bb1[j];
    }
    if (tid == 0) s_fob = fob[0];
    if (tid >= 192 && tid < 192 + NL) {
        int l = tid - 192;
        const float* cm = Cm + ((size_t)b * NL + l) * 12;
        float denom = cm[9] + 0.05f;
        float s = 63.5f / (0.55f * denom);
        s_cam[l][0] = cm[0] * s; s_cam[l][1] = cm[1] * s; s_cam[l][2] = cm[2] * s;
        s_cam[l][3] = cm[3] * s; s_cam[l][4] = cm[4] * s; s_cam[l][5] = cm[5] * s;
    }
    __syncthreads();

    const int lane = tid & 63;
    const int wv = tid >> 6;
    const int q = lane >> 4;       // quad: owns channels 8q..8q+7
    const int i16 = lane & 15;     // point within wave
    const int t = blockIdx.x * 64 + wv * 16 + i16;
    const int tc = min(t, NT - 1);

    const float* pp = p + ((size_t)b * NT + tc) * 3;
    float px = pp[0], py = pp[1], pz = pp[2];

    // ---- bilinear multi-view gather: lane loads only its 8 channels ----
    float feat[8];
    #pragma unroll
    for (int u = 0; u < 8; u++) feat[u] = 0.f;
    const float* cq = c + (((size_t)b * NL) << 19) + q * 8;
    #pragma unroll 1
    for (int l = 0; l < NL; l++) {
        float x = s_cam[l][0] * px + s_cam[l][1] * py + s_cam[l][2] * pz + 63.5f;
        float y = s_cam[l][3] * px + s_cam[l][4] * py + s_cam[l][5] * pz + 63.5f;
        float x0f = floorf(x), x1f = ceilf(x);
        float y0f = floorf(y), y1f = ceilf(y);
        float dxw = x1f - x, dyw = y1f - y;
        int x0 = min(max((int)x0f, 0), 127);
        int x1 = min(max((int)x1f, 0), 127);
        int y0 = min(max((int)y0f, 0), 127);
        int y1 = min(max((int)y1f, 0), 127);
        const float* base = cq + ((size_t)l << 19);
        const floatx4* f11 = (const floatx4*)(base + (size_t)((x0 << 7) + y0) * 32);
        const floatx4* f12 = (const floatx4*)(base + (size_t)((x1 << 7) + y0) * 32);
        const floatx4* f21 = (const floatx4*)(base + (size_t)((x0 << 7) + y1) * 32);
        const floatx4* f22 = (const floatx4*)(base + (size_t)((x1 << 7) + y1) * 32);
        float w11 = dxw * dyw;
        float w12 = (1.f - dxw) * dyw;
        float w21 = dxw * (1.f - dyw);
        float w22 = (1.f - dxw) * (1.f - dyw);
        floatx4 a0 = f11[0], a1 = f11[1];
        floatx4 b0v = f12[0], b1v = f12[1];
        floatx4 c0 = f21[0], c1 = f21[1];
        floatx4 d0 = f22[0], d1 = f22[1];
        #pragma unroll
        for (int u = 0; u < 4; u++) {
            feat[u]     += a0[u] * w11 + b0v[u] * w12 + c0[u] * w21 + d0[u] * w22;
            feat[4 + u] += a1[u] * w11 + b1v[u] * w12 + c1[u] * w21 + d1[u] * w22;
        }
    }

    // ---- blk0: h = b0b0 + W0_perm @ relu(fc_p(p)), K=256 via 8 chunks of 32 ----
    floatx4 acc0 = *(const floatx4*)&s_b0b0[q * 8];
    floatx4 acc1 = *(const floatx4*)&s_b0b0[q * 8 + 4];
    const f16* w0row0 = s_w0A + i16 * 288;
    const f16* w0row1 = s_w0A + (16 + i16) * 288;
    #pragma unroll 2
    for (int cch = 0; cch < 8; cch++) {
        half8 bf;
        #pragma unroll
        for (int j = 0; j < 8; j++) {
            floatx4 w = s_fcp[cch * 36 + q * 9 + j];
            bf[j] = (f16)fmaxf(w[0] * px + w[1] * py + w[2] * pz + w[3], 0.f);
        }
        half8 a0 = *(const half8*)(w0row0 + cch * 32 + q * 8);
        half8 a1 = *(const half8*)(w0row1 + cch * 32 + q * 8);
        acc0 = __builtin_amdgcn_mfma_f32_16x16x32_f16(a0, bf, acc0, 0, 0, 0);
        acc1 = __builtin_amdgcn_mfma_f32_16x16x32_f16(a1, bf, acc1, 0, 0, 0);
    }

    // ---- blk0 second layer: dx = b0b1 + W1_perm @ relu(h); state = dx + fold(p) + feat
    float hbuf[8];
    #pragma unroll
    for (int r = 0; r < 4; r++) { hbuf[r] = acc0[r]; hbuf[4 + r] = acc1[r]; }
    floatx4 n0 = *(const floatx4*)&s_b0b1[q * 8];
    floatx4 n1 = *(const floatx4*)&s_b0b1[q * 8 + 4];
    gemm32(s_wA, i16, q, hbuf, n0, n1);

    float st[8];
    #pragma unroll
    for (int j = 0; j < 8; j++) {
        floatx4 f = s_fold[q * 9 + j];
        float sc = f[0] * px + f[1] * py + f[2] * pz + f[3];
        st[j] = ((j < 4) ? n0[j] : n1[j - 4]) + sc + feat[j];
    }

    // ---- residual blocks ----
    #pragma unroll
    for (int bk = 0; bk < 4; bk++) {
        floatx4 h0 = *(const floatx4*)&s_bb0f[bk * 32 + q * 8];
        floatx4 h1 = *(const floatx4*)&s_bb0f[bk * 32 + q * 8 + 4];
        gemm32(s_wA + (1 + 2 * bk) * 1280, i16, q, st, h0, h1);
        float hb[8];
        #pragma unroll
        for (int r = 0; r < 4; r++) { hb[r] = h0[r]; hb[4 + r] = h1[r]; }
        floatx4 d0 = *(const floatx4*)&s_bb1f[bk * 32 + q * 8];
        floatx4 d1 = *(const floatx4*)&s_bb1f[bk * 32 + q * 8 + 4];
        gemm32(s_wA + (2 + 2 * bk) * 1280, i16, q, hb, d0, d1);
        #pragma unroll
        for (int j = 0; j < 8; j++)
            st[j] += ((j < 4) ? d0[j] : d1[j - 4]) + feat[j];
    }

    // ---- head: per-lane partial dot, reduce across quads ----
    floatx4 fw0 = *(const floatx4*)&s_fow[q * 8];
    floatx4 fw1 = *(const floatx4*)&s_fow[q * 8 + 4];
    float o = 0.f;
    #pragma unroll
    for (int r = 0; r < 4; r++)
        o += fmaxf(st[r], 0.f) * fw0[r] + fmaxf(st[4 + r], 0.f) * fw1[r];
    o += __shfl_xor(o, 16);
    o += __shfl_xor(o, 32);
    if (q == 0 && t < NT) out[(size_t)b * NT + t] = o + s_fob;
}

extern "C" void kernel_launch(void* const* d_in, const int* in_sizes, int n_in,
                              void* d_out, int out_size, void* d_ws, size_t ws_size,
                              hipStream_t stream) {
    const float* p    = (const float*)d_in[0];
    const float* c    = (const float*)d_in[2];
    const float* Cm   = (const float*)d_in[3];
    const float* fpw  = (const float*)d_in[4];
    const float* fpb  = (const float*)d_in[5];
    const float* b0w0 = (const float*)d_in[6];
    const float* b0b0 = (const float*)d_in[7];
    const float* b0w1 = (const float*)d_in[8];
    const float* b0b1 = (const float*)d_in[9];
    const float* b0ws = (const float*)d_in[10];
    const float* bw0  = (const float*)d_in[11];
    const float* bb0  = (const float*)d_in[12];
    const float* bw1  = (const float*)d_in[13];
    const float* bb1  = (const float*)d_in[14];
    const float* fow  = (const float*)d_in[15];
    const float* fob  = (const float*)d_in[16];
    floatx4* fold = (floatx4*)d_ws;

    fold_kernel<<<1, 64, 0, stream>>>(b0ws, fpw, fpb, fold);

    dim3 grid((NT + 63) / 64, NB);
    decoder_kernel<<<grid, 256, 0, stream>>>(p, c, Cm, fpw, fpb,
                                             b0w0, b0b0, b0w1, b0b1,
                                             bw0, bb0, bw1, bb1,
                                             fow, fob, fold, (float*)d_out);
}